// Round 1
// baseline (441.779 us; speedup 1.0000x reference)
//
#include <hip/hip_runtime.h>
#include <hip/hip_bf16.h>

// MultiHeadAttention: x(2,4096,768) @ W_qkv(768,2304) + b -> split q,k,v (H=8, dh=96)
// scores = q.k^T * 768^-0.5, softmax, out = attn @ v. Output fp32 (2,4096,768).
// Strategy: bf16 MFMA for both GEMMs (fp32 accum), flash-style online softmax.

typedef __attribute__((ext_vector_type(8))) short     bf16x8;  // MFMA A/B frag (4 VGPRs)
typedef __attribute__((ext_vector_type(4))) float     floatx4; // MFMA C/D frag
typedef __attribute__((ext_vector_type(8))) unsigned short us8; // 16B vector ld/st
typedef __attribute__((ext_vector_type(4))) unsigned short us4; // 8B vector st

#define HEADS 8
#define DH 96
#define NSEQ 4096
#define DIM 768
#define SCALE_F 0.03608439182435161f  /* 768^-0.5 */

__device__ __forceinline__ unsigned short f2bf(float f) {
    union { float f; unsigned u; } v; v.f = f;
    unsigned r = v.u + 0x7fffu + ((v.u >> 16) & 1u);  // RN-even
    return (unsigned short)(r >> 16);
}

// ---------------- convert x (fp32) -> xb (bf16), 8192x768 row-major ----------------
__global__ __launch_bounds__(256) void cvt_x(const float* __restrict__ x, unsigned short* __restrict__ xb) {
    int i = blockIdx.x * 256 + threadIdx.x;       // one float4 per thread, 6291456/4 total
    float4 v = ((const float4*)x)[i];
    us4 o; o.x = f2bf(v.x); o.y = f2bf(v.y); o.z = f2bf(v.z); o.w = f2bf(v.w);
    ((us4*)xb)[i] = o;
}

// ------------- convert W (768x2304 fp32) -> Wt (2304x768 bf16, transposed) ---------
__global__ __launch_bounds__(256) void cvt_w(const float* __restrict__ w, unsigned short* __restrict__ wt) {
    __shared__ unsigned short sm[64][33];          // [k][c] tile, padded
    int c0 = blockIdx.x * 32, k0 = blockIdx.y * 64;
    int t = threadIdx.x;
    int cl = t & 31, kl0 = t >> 5;                 // 0..31, 0..7
    for (int i = 0; i < 8; ++i) {
        int kl = kl0 + i * 8;
        sm[kl][cl] = f2bf(w[(k0 + kl) * 2304 + c0 + cl]);
    }
    __syncthreads();
    int kl2 = t & 63, cl0 = t >> 6;                // 0..63, 0..3
    for (int i = 0; i < 8; ++i) {
        int cl2 = cl0 + i * 4;
        wt[(c0 + cl2) * 768 + k0 + kl2] = sm[kl2][cl2];
    }
}

// ---------------- QKV GEMM: C(8192x2304) = xb @ Wt^T + bias ------------------------
// 128x128 tile, BK=64, 4 waves each 64x64 of 16x16x32 MFMA.
// Epilogue scatters: q (scaled) / k row-major [bh][n][d], v transposed [bh][d][n], all bf16.
__global__ __launch_bounds__(256) void gemm_qkv(const unsigned short* __restrict__ xb,
                                                const unsigned short* __restrict__ wt,
                                                const float* __restrict__ bias,
                                                unsigned short* __restrict__ qb,
                                                unsigned short* __restrict__ kb,
                                                unsigned short* __restrict__ vt) {
    __shared__ unsigned short As[128 * 72];        // stride 72: 2-way banks max
    __shared__ unsigned short Bs[128 * 72];
    const int tid = threadIdx.x;
    const int lane = tid & 63, wv = tid >> 6;
    const int n15 = lane & 15, quad = lane >> 4;
    const int m0 = blockIdx.y * 128, c0 = blockIdx.x * 128;
    const int mw = (wv >> 1) * 64, nw = (wv & 1) * 64;
    floatx4 acc[4][4] = {};

    for (int kt = 0; kt < 12; ++kt) {
        for (int i = 0; i < 4; ++i) {
            int g = i * 256 + tid;                 // 0..1023 : 128 rows x 8 groups
            int row = g >> 3, gc = g & 7;
            *(us8*)&As[row * 72 + gc * 8] = *(const us8*)&xb[(m0 + row) * 768 + kt * 64 + gc * 8];
            *(us8*)&Bs[row * 72 + gc * 8] = *(const us8*)&wt[(c0 + row) * 768 + kt * 64 + gc * 8];
        }
        __syncthreads();
        for (int ks = 0; ks < 2; ++ks) {
            bf16x8 af[4], bfr[4];
            for (int mt = 0; mt < 4; ++mt)
                af[mt] = *(const bf16x8*)&As[(mw + mt * 16 + n15) * 72 + ks * 32 + quad * 8];
            for (int nt = 0; nt < 4; ++nt)
                bfr[nt] = *(const bf16x8*)&Bs[(nw + nt * 16 + n15) * 72 + ks * 32 + quad * 8];
            for (int mt = 0; mt < 4; ++mt)
                for (int nt = 0; nt < 4; ++nt)
                    acc[mt][nt] = __builtin_amdgcn_mfma_f32_16x16x32_bf16(af[mt], bfr[nt], acc[mt][nt], 0, 0, 0);
        }
        __syncthreads();
    }
    // epilogue: c = which*768 + h*96 + d
    for (int nt = 0; nt < 4; ++nt) {
        int c = c0 + nw + nt * 16 + n15;
        float bv = bias[c];
        int which = c / 768, rem = c % 768;
        int h = rem / 96, d = rem % 96;
        for (int mt = 0; mt < 4; ++mt) {
            for (int r = 0; r < 4; ++r) {
                int m = m0 + mw + mt * 16 + quad * 4 + r;
                int b = m >> 12, n = m & 4095;
                float val = acc[mt][nt][r] + bv;
                int bh = b * HEADS + h;
                if (which == 0)      qb[(bh * NSEQ + n) * DH + d] = f2bf(val * SCALE_F);
                else if (which == 1) kb[(bh * NSEQ + n) * DH + d] = f2bf(val);
                else                 vt[(bh * DH + d) * NSEQ + n] = f2bf(val);
            }
        }
    }
}

// ---------------- Flash attention: WG = (64 Q-rows) x (bh); KV tiles of 64 ---------
// 4 waves x 16 Q-rows. S via 16x16x32 MFMA; online softmax in registers (C-layout:
// row = quad*4+reg, col = lane&15); P -> LDS strip -> A-layout (m=lane&15, k=quad*8+j).
__global__ __launch_bounds__(256) void flash(const unsigned short* __restrict__ qb,
                                             const unsigned short* __restrict__ kb,
                                             const unsigned short* __restrict__ vt,
                                             float* __restrict__ out) {
    __shared__ unsigned short sm[24832];           // 49664 B
    unsigned short* Qs = sm;                       // 64 x 104 (pad: 2-way banks)
    unsigned short* Ks = sm + 6656;                // 64 x 104
    unsigned short* Vt = sm + 13312;               // 96 x 72
    unsigned short* Ps = sm + 20224;               // 4 waves x 16 x 72

    const int tid = threadIdx.x;
    const int lane = tid & 63, wv = tid >> 6;
    const int n15 = lane & 15, quad = lane >> 4;
    const int bh = blockIdx.y;
    const int q0 = blockIdx.x * 64;

    // stage Q tile (reused across all KV iterations)
    for (int i = 0; i < 3; ++i) {
        int g = i * 256 + tid;                     // 0..767 : 64 rows x 12 groups
        int row = g / 12, gc = g % 12;
        *(us8*)&Qs[row * 104 + gc * 8] = *(const us8*)&qb[(bh * NSEQ + q0 + row) * DH + gc * 8];
    }

    floatx4 o[6] = {};
    float m_i[4], l_i[4];
    for (int r = 0; r < 4; ++r) { m_i[r] = -1e30f; l_i[r] = 0.f; }

    for (int kv = 0; kv < 64; ++kv) {
        int kv0 = kv * 64;
        for (int i = 0; i < 3; ++i) {
            int g = i * 256 + tid;
            int row = g / 12, gc = g % 12;
            *(us8*)&Ks[row * 104 + gc * 8] = *(const us8*)&kb[(bh * NSEQ + kv0 + row) * DH + gc * 8];
        }
        for (int i = 0; i < 3; ++i) {
            int g = i * 256 + tid;                 // 96 rows x 8 groups
            int d = g >> 3, gc = g & 7;
            *(us8*)&Vt[d * 72 + gc * 8] = *(const us8*)&vt[(bh * DH + d) * NSEQ + kv0 + gc * 8];
        }
        __syncthreads();

        // S = Q K^T (scale pre-folded into q)
        floatx4 sc[4] = {};
        for (int ks = 0; ks < 3; ++ks) {
            bf16x8 aq = *(const bf16x8*)&Qs[(wv * 16 + n15) * 104 + ks * 32 + quad * 8];
            for (int nt = 0; nt < 4; ++nt) {
                bf16x8 bk = *(const bf16x8*)&Ks[(nt * 16 + n15) * 104 + ks * 32 + quad * 8];
                sc[nt] = __builtin_amdgcn_mfma_f32_16x16x32_bf16(aq, bk, sc[nt], 0, 0, 0);
            }
        }

        // online softmax over the 64 new columns
        float mloc[4];
        for (int r = 0; r < 4; ++r)
            mloc[r] = fmaxf(fmaxf(sc[0][r], sc[1][r]), fmaxf(sc[2][r], sc[3][r]));
        for (int off = 1; off < 16; off <<= 1)
            for (int r = 0; r < 4; ++r)
                mloc[r] = fmaxf(mloc[r], __shfl_xor(mloc[r], off));
        float alpha[4], psum[4];
        for (int r = 0; r < 4; ++r) {
            float mn = fmaxf(m_i[r], mloc[r]);
            alpha[r] = __expf(m_i[r] - mn);
            m_i[r] = mn;
            psum[r] = 0.f;
        }
        for (int nt = 0; nt < 4; ++nt)
            for (int r = 0; r < 4; ++r) {
                float p = __expf(sc[nt][r] - m_i[r]);
                sc[nt][r] = p;
                psum[r] += p;
            }
        for (int off = 1; off < 16; off <<= 1)
            for (int r = 0; r < 4; ++r)
                psum[r] += __shfl_xor(psum[r], off);
        for (int r = 0; r < 4; ++r) l_i[r] = l_i[r] * alpha[r] + psum[r];
        for (int t = 0; t < 6; ++t)
            for (int r = 0; r < 4; ++r) o[t][r] *= alpha[r];

        // P (C-layout) -> LDS -> A-layout for PV. Per-wave strip: no cross-wave hazard.
        unsigned short* pw = Ps + wv * 1152;
        for (int nt = 0; nt < 4; ++nt)
            for (int r = 0; r < 4; ++r)
                pw[(quad * 4 + r) * 72 + nt * 16 + n15] = f2bf(sc[nt][r]);

        for (int ks = 0; ks < 2; ++ks) {
            bf16x8 ap = *(const bf16x8*)&Ps[wv * 1152 + n15 * 72 + ks * 32 + quad * 8];
            for (int t = 0; t < 6; ++t) {
                bf16x8 bv = *(const bf16x8*)&Vt[(t * 16 + n15) * 72 + ks * 32 + quad * 8];
                o[t] = __builtin_amdgcn_mfma_f32_16x16x32_bf16(ap, bv, o[t], 0, 0, 0);
            }
        }
        __syncthreads();  // protect Ks/Vt before next iteration's staging
    }

    // epilogue: out[b][n][h*96+d], fp32
    int b = bh >> 3, h = bh & 7;
    for (int r = 0; r < 4; ++r) {
        float inv = 1.0f / l_i[r];
        int n = q0 + wv * 16 + quad * 4 + r;
        float* op = out + (size_t)(b * NSEQ + n) * DIM + h * DH;
        for (int t = 0; t < 6; ++t)
            op[t * 16 + n15] = o[t][r] * inv;
    }
}

extern "C" void kernel_launch(void* const* d_in, const int* in_sizes, int n_in,
                              void* d_out, int out_size, void* d_ws, size_t ws_size,
                              hipStream_t stream) {
    const float* x    = (const float*)d_in[0];   // 2*4096*768
    const float* W    = (const float*)d_in[1];   // 768*2304
    const float* bias = (const float*)d_in[2];   // 2304
    float* out = (float*)d_out;

    char* ws = (char*)d_ws;
    unsigned short* xb = (unsigned short*)(ws);                    // 8192*768 bf16
    unsigned short* wt = (unsigned short*)(ws + 12582912);         // 2304*768 bf16 (transposed)
    unsigned short* qb = (unsigned short*)(ws + 16121856);         // [16][4096][96]
    unsigned short* kb = (unsigned short*)(ws + 28704768);         // [16][4096][96]
    unsigned short* vt = (unsigned short*)(ws + 41287680);         // [16][96][4096]
    // total ws use: 53,870,592 B

    cvt_x<<<6144, 256, 0, stream>>>(x, xb);
    cvt_w<<<dim3(72, 12), 256, 0, stream>>>(W, wt);
    gemm_qkv<<<dim3(18, 64), 256, 0, stream>>>(xb, wt, bias, qb, kb, vt);
    flash<<<dim3(64, 16), 256, 0, stream>>>(qb, kb, vt, out);
}